// Round 7
// baseline (685.578 us; speedup 1.0000x reference)
//
#include <hip/hip_runtime.h>
#include <hip/hip_bf16.h>
#include <stdint.h>

// HydraAttention: out[b,t,d] = q[b,t,d] * Skv[b,d] / sqrt(Sqq[b,d]*Skk[b,d])
// qkv = x@W + b. B=4 T=4096 D=2048. GEMM M=16384 N=6144 K=2048, bf16 MFMA.
// Round 7: occupancy attack. 1024-thr / 16-wave block (4x4 waves of 64x64),
// BM=BN=256, BK=32, LDS 64 KiB dbuf -> VGPR<=128 target -> 4 waves/SIMD.
// BK=32 rows are 64B => frag ds_read_b128 covers contiguous 1KiB => zero bank
// conflicts with NO swizzle; staging is linear. One barrier per subtile.

#define DMODEL 2048
#define TSEQ   4096
#define MM     16384
#define NN     6144
#define KK     2048

typedef unsigned short u16;
typedef __bf16 bf16x8 __attribute__((ext_vector_type(8)));
typedef float  f32x4  __attribute__((ext_vector_type(4)));
typedef u16    u16x8  __attribute__((ext_vector_type(8)));

__device__ __forceinline__ u16 f2bf(float f) {
    unsigned u = __float_as_uint(f);
    u += 0x7fffu + ((u >> 16) & 1u);   // RNE
    return (u16)(u >> 16);
}
__device__ __forceinline__ float bf2f(u16 h) {
    return __uint_as_float(((unsigned)h) << 16);
}

// ---------------- pass 1a: x (f32) -> xb (bf16) ----------------
__global__ void cvt_x_kernel(const float* __restrict__ x, u16* __restrict__ xb) {
    long i = ((long)blockIdx.x * 256 + threadIdx.x) * 8;
    float4 a = *(const float4*)(x + i);
    float4 b = *(const float4*)(x + i + 4);
    u16x8 o;
    o[0] = f2bf(a.x); o[1] = f2bf(a.y); o[2] = f2bf(a.z); o[3] = f2bf(a.w);
    o[4] = f2bf(b.x); o[5] = f2bf(b.y); o[6] = f2bf(b.z); o[7] = f2bf(b.w);
    *(u16x8*)(xb + i) = o;
}

// ---------------- pass 1b: W (K x N f32) -> Wt (N x K bf16) ----------------
__global__ void cvt_wt_kernel(const float* __restrict__ W, u16* __restrict__ wt) {
    __shared__ u16 tile[64][65];
    const int k0 = blockIdx.x * 64;
    const int n0 = blockIdx.y * 64;
    const int t  = threadIdx.x;
#pragma unroll
    for (int p = 0; p < 16; ++p) {
        int idx = p * 256 + t;
        int kk = idx >> 6, nn = idx & 63;
        tile[kk][nn] = f2bf(W[(long)(k0 + kk) * NN + n0 + nn]);
    }
    __syncthreads();
#pragma unroll
    for (int p = 0; p < 16; ++p) {
        int idx = p * 256 + t;
        int nn = idx >> 6, kk = idx & 63;
        wt[(long)(n0 + nn) * KK + k0 + kk] = tile[kk][nn];
    }
}

// ---------------- pass 2: 256^2-tile 16-wave bf16 MFMA GEMM, BK=32 ----------------
// A = xb (M x K), B = wt (N x K), k-contiguous. 1024 threads = 16 waves (4M x 4N).
// Per wave: 64x64 output = 4x4 frags of 16x16x32, acc = 64 regs.
// LDS: 2 dbuf x (A 256x32 + B 256x32) x 2B = 64 KiB. 64 K-subtiles.
// Per subtile: {stage s+1 (2 gload_lds) ; read 4 A + 4 B b128 ; 16 MFMA ; VMW(0) ; BAR}.
// Stage: thread t covers row t>>2, 16B-chunk t&3 (linear, no swizzle).
// Frag reads cover contiguous 1KiB per 16-row group -> conflict-free unswizzled.

#define BAR()   __builtin_amdgcn_s_barrier()
#define VMW(n)  asm volatile("s_waitcnt vmcnt(" #n ")" ::: "memory")
#define PRIO(x) __builtin_amdgcn_s_setprio(x)

__global__ __launch_bounds__(1024, 4) void gemm_qkv_16w(
        const u16* __restrict__ xb, const u16* __restrict__ wt,
        const float* __restrict__ bias, float* __restrict__ qout,
        u16* __restrict__ kb, u16* __restrict__ vb) {
    __shared__ u16 smem[2][2][256 * 32];   // [buf][A/B][row*32 + elem] = 64 KiB

    const int tid = threadIdx.x;
    const int l = tid & 63, w = tid >> 6;      // 16 waves
    const int wm = w >> 2, wn = w & 3;         // 4 x 4
    const int lr = l & 15, lk = l >> 4;

    // XCD-aware bijective swizzle (nwg = 1536, 1536 % 8 == 0)
    int bid = (int)blockIdx.x;
    int swz = (bid & 7) * (1536 / 8) + (bid >> 3);
    const int m0 = (swz & 63) * 256;
    const int n0 = (swz >> 6) * 256;

    // staging: thread t -> row t>>2 (0..255), 16B chunk t&3; advance 32 elems/subtile
    const u16* gA = xb + (long)(m0 + (tid >> 2)) * KK + (tid & 3) * 8;
    const u16* gB = wt + (long)(n0 + (tid >> 2)) * KK + (tid & 3) * 8;

    // frag read offsets (u16 elems): row*32 + lk*8; rows wm*64+m*16+lr / wn*64+n*16+lr
    const int aoff = (wm * 64 + lr) * 32 + lk * 8;
    const int boff = (wn * 64 + lr) * 32 + lk * 8;

    f32x4 acc[4][4] = {};

#define STAGE(buf, ss) do {                                                        \
    __builtin_amdgcn_global_load_lds(                                              \
        (__attribute__((address_space(1))) void*)(u16*)(gA + (ss) * 32),           \
        (__attribute__((address_space(3))) void*)&smem[buf][0][w * 512], 16, 0, 0);\
    __builtin_amdgcn_global_load_lds(                                              \
        (__attribute__((address_space(1))) void*)(u16*)(gB + (ss) * 32),           \
        (__attribute__((address_space(3))) void*)&smem[buf][1][w * 512], 16, 0, 0);\
    } while (0)

#define SUBTILE(cb, nb, en, snext) do {                                            \
    if (en) STAGE(nb, snext);                                                      \
    bf16x8 Af[4], Bf[4];                                                           \
    _Pragma("unroll")                                                              \
    for (int m_ = 0; m_ < 4; ++m_) Af[m_] = *(const bf16x8*)&smem[cb][0][aoff + m_ * 512]; \
    _Pragma("unroll")                                                              \
    for (int n_ = 0; n_ < 4; ++n_) Bf[n_] = *(const bf16x8*)&smem[cb][1][boff + n_ * 512]; \
    PRIO(1);                                                                       \
    _Pragma("unroll")                                                              \
    for (int m_ = 0; m_ < 4; ++m_) {                                               \
        _Pragma("unroll")                                                          \
        for (int n_ = 0; n_ < 4; ++n_)                                             \
            acc[m_][n_] = __builtin_amdgcn_mfma_f32_16x16x32_bf16(                 \
                Af[m_], Bf[n_], acc[m_][n_], 0, 0, 0);                             \
    }                                                                              \
    PRIO(0);                                                                       \
    VMW(0); BAR(); } while (0)

    // prologue: stage subtile 0 into buf 0, land it.
    STAGE(0, 0);
    VMW(0); BAR();

    for (int s = 0; s < 64; s += 2) {
        SUBTILE(0, 1, true, s + 1);            // s+1 <= 63 always here
        SUBTILE(1, 0, (s + 2 < 64), s + 2);
    }

    // epilogue: + bias, route by region. C/D: col=lane&15, row=(lane>>4)*4+reg.
    float bv[4];
#pragma unroll
    for (int n_ = 0; n_ < 4; ++n_) bv[n_] = bias[n0 + wn * 64 + n_ * 16 + lr];

#pragma unroll
    for (int mi = 0; mi < 4; ++mi) {
#pragma unroll
        for (int n_ = 0; n_ < 4; ++n_) {
            int gn = n0 + wn * 64 + n_ * 16 + lr;
#pragma unroll
            for (int j = 0; j < 4; ++j) {
                int gm = m0 + wm * 64 + mi * 16 + lk * 4 + j;
                float val = acc[mi][n_][j] + bv[n_];
                if (n0 < DMODEL) {
                    qout[(long)gm * DMODEL + gn] = val;
                } else if (n0 < 2 * DMODEL) {
                    kb[(long)gm * DMODEL + (gn - DMODEL)] = f2bf(val);
                } else {
                    vb[(long)gm * DMODEL + (gn - 2 * DMODEL)] = f2bf(val);
                }
            }
        }
    }
#undef STAGE
#undef SUBTILE
}

// ---------------- pass 3: per-(b,d) reductions Sqq, Skk, Skv ----------------
__global__ void reduce_kernel(const float* __restrict__ q, const u16* __restrict__ kb,
                              const u16* __restrict__ vb, float* __restrict__ sums) {
    const int b  = blockIdx.x >> 7;
    const int tc = blockIdx.x & 127;
    const long row0 = (long)b * TSEQ + tc * 32;
    const int d0 = threadIdx.x * 8;
    float aqq[8] = {}, akk[8] = {}, akv[8] = {};
    for (int r = 0; r < 32; ++r) {
        long base = (row0 + r) * (long)DMODEL + d0;
        float4 q0 = *(const float4*)(q + base);
        float4 q1 = *(const float4*)(q + base + 4);
        u16x8 k8 = *(const u16x8*)(kb + base);
        u16x8 v8 = *(const u16x8*)(vb + base);
        float qa[8] = {q0.x, q0.y, q0.z, q0.w, q1.x, q1.y, q1.z, q1.w};
#pragma unroll
        for (int j = 0; j < 8; ++j) {
            float kf = bf2f(k8[j]), vf = bf2f(v8[j]);
            aqq[j] += qa[j] * qa[j];
            akk[j] += kf * kf;
            akv[j] += kf * vf;
        }
    }
    const int sbase = b * DMODEL + d0;
#pragma unroll
    for (int j = 0; j < 8; ++j) {
        atomicAdd(&sums[sbase + j],         aqq[j]);
        atomicAdd(&sums[8192 + sbase + j],  akk[j]);
        atomicAdd(&sums[16384 + sbase + j], akv[j]);
    }
}

// ---------------- pass 4: s = Skv / sqrt(Sqq*Skk) ----------------
__global__ void finalize_kernel(const float* __restrict__ sums, float* __restrict__ s) {
    int i = blockIdx.x * 256 + threadIdx.x;
    float sqq = sums[i], skk = sums[8192 + i], skv = sums[16384 + i];
    s[i] = skv / sqrtf(sqq * skk);
}

// ---------------- pass 5: out *= s[b,d] ----------------
__global__ void scale_kernel(float* __restrict__ out, const float* __restrict__ s) {
    long e = ((long)blockIdx.x * 256 + threadIdx.x) * 4;
    int d = (int)(e & (DMODEL - 1));
    int b = (int)(e >> 23);
    float4 v  = *(float4*)(out + e);
    float4 sv = *(const float4*)(s + b * DMODEL + d);
    v.x *= sv.x; v.y *= sv.y; v.z *= sv.z; v.w *= sv.w;
    *(float4*)(out + e) = v;
}

extern "C" void kernel_launch(void* const* d_in, const int* in_sizes, int n_in,
                              void* d_out, int out_size, void* d_ws, size_t ws_size,
                              hipStream_t stream) {
    const float* x    = (const float*)d_in[0];
    const float* W    = (const float*)d_in[1];
    const float* bias = (const float*)d_in[2];
    float* out = (float*)d_out;

    char* ws = (char*)d_ws;
    u16*   xb   = (u16*)(ws);                         //  64 MiB
    u16*   wt   = (u16*)(ws + 67108864L);             //  24 MiB
    u16*   kb   = (u16*)(ws + 92274688L);             //  64 MiB
    u16*   vb   = (u16*)(ws + 159383552L);            //  64 MiB
    float* sums = (float*)(ws + 226492416L);          //  96 KiB
    float* sc   = (float*)(ws + 226492416L + 98304L); //  32 KiB

    hipMemsetAsync(sums, 0, 3 * 8192 * sizeof(float), stream);
    cvt_x_kernel<<<16384, 256, 0, stream>>>(x, xb);
    cvt_wt_kernel<<<dim3(KK / 64, NN / 64), 256, 0, stream>>>(W, wt);
    gemm_qkv_16w<<<1536, 1024, 0, stream>>>(xb, wt, bias, out, kb, vb);
    reduce_kernel<<<512, 256, 0, stream>>>(out, kb, vb, sums);
    finalize_kernel<<<32, 256, 0, stream>>>(sums, sc);
    scale_kernel<<<32768, 256, 0, stream>>>(out, sc);
}